// Round 15
// baseline (60.547 us; speedup 1.0000x reference)
//
#include <hip/hip_runtime.h>
#include <hip/hip_bf16.h>

#define BB 16
#define SS 512
#define HH 1024

typedef __attribute__((ext_vector_type(4))) float f32x4;
typedef __attribute__((ext_vector_type(8))) short bhalf8;

static __device__ __forceinline__ unsigned int pack2(float a, float b) {
    __hip_bfloat162 h = __float22bfloat162_rn(make_float2(a, b));
    union { __hip_bfloat162 h; unsigned int u; } cv;
    cv.h = h;
    return cv.u;
}

// ---------------------------------------------------------------------------
// Prepass (all coalesced):
//   blocks [0,2048):    W[e][k][d] -> Wt[e][d][k] bf16 via LDS transpose
//   blocks [2048,6144): hid f32 -> hidb bf16
// ---------------------------------------------------------------------------
__global__ __launch_bounds__(256)
void prep_kernel(const float* __restrict__ W, const float* __restrict__ hid,
                 const int* __restrict__ eidx, unsigned short* __restrict__ Wt,
                 unsigned short* __restrict__ hidb)
{
    int bid = blockIdx.x;
    int t = threadIdx.x;
    if (bid < 2048) {
        __shared__ float lds[32 * 132];
        int e  = bid >> 8;
        bool used = false;
        for (int b = 0; b < BB; ++b) used = used || (eidx[b] == e);
        if (!used) return;
        int rem = bid & 255;
        int kt = rem >> 3, dt = rem & 7;     // 32-k x 128-d tile
#pragma unroll
        for (int i = 0; i < 4; ++i) {
            int idx = t + i * 256;
            int row = idx >> 5, col4 = idx & 31;
            float4 v = *(const float4*)(W + ((size_t)e << 20)
                        + (size_t)(kt * 32 + row) * HH + dt * 128 + col4 * 4);
            float* dst = &lds[row * 132 + col4 * 4];
            dst[0] = v.x; dst[1] = v.y; dst[2] = v.z; dst[3] = v.w;
        }
        __syncthreads();
        int d = t >> 1, kh = t & 1;
        unsigned int u[8];
#pragma unroll
        for (int p = 0; p < 8; ++p) {
            float a = lds[(kh * 16 + p * 2)     * 132 + d];
            float b = lds[(kh * 16 + p * 2 + 1) * 132 + d];
            u[p] = pack2(a, b);
        }
        unsigned short* dst = Wt + ((size_t)e << 20)
                            + (size_t)(dt * 128 + d) * HH + kt * 32 + kh * 16;
        *reinterpret_cast<uint4*>(dst)     = make_uint4(u[0], u[1], u[2], u[3]);
        *reinterpret_cast<uint4*>(dst + 8) = make_uint4(u[4], u[5], u[6], u[7]);
    } else {
        int bid2 = bid - 2048;               // 2 rows per block
        int r = bid2 * 2 + (t >> 7);
        int col = (t & 127) * 8;
        const float* src = hid + (size_t)r * HH + col;
        float4 v0 = *(const float4*)(src);
        float4 v1 = *(const float4*)(src + 4);
        uint4 o;
        o.x = pack2(v0.x, v0.y); o.y = pack2(v0.z, v0.w);
        o.z = pack2(v1.x, v1.y); o.w = pack2(v1.z, v1.w);
        *reinterpret_cast<uint4*>(hidb + (size_t)r * HH + col) = o;
    }
}

// ---------------------------------------------------------------------------
// PURE GEMM: y = hid @ W[e]. R8's verified body at 3 blocks/CU.
// 512 blocks x 256 thr (4 waves, 2x2 of 64x64), tile 128x128, BK=32,
// TRIPLE-buffered LDS (48KB -> 3 resident blocks/CU = 12 waves/CU),
// counted vmcnt: stage k+2 ahead (4 loads/thread/stage), steady vmcnt(4),
// tail 4->0. pair-line XOR LDS layout (verified 0 conflicts),
// mfma 16x16x32 bf16 (16/wave/iter vs 8 ds_read_b128: 2:1).
// ---------------------------------------------------------------------------
__global__ __launch_bounds__(256, 3)
void gemm8_kernel(const unsigned short* __restrict__ hidb,
                  const int* __restrict__ eidx,
                  const unsigned short* __restrict__ Wt,
                  float* __restrict__ out)
{
    __shared__ char ldsA[3 * 8192];    // A: bf16 [128 r][32 k] per buf
    __shared__ char ldsW[3 * 8192];    // W: bf16 [128 d][32 k] per buf

    int bx  = blockIdx.x;
    int swz = (bx & 7) * 64 + (bx >> 3);      // XCD-bijective (512 % 8 == 0)
    int bt   = swz >> 5;                      // batch 0..15
    int tile = swz & 31;
    int mt = tile >> 3, nt = tile & 7;        // 4 m-tiles x 8 n-tiles
    int e = eidx[bt];

    int t = threadIdx.x, wave = t >> 6, lane = t & 63;
    int l15 = lane & 15, g = lane >> 4;
    int wm = wave >> 1, wn = wave & 1;        // 2x2 wave grid, 64x64 each

    int brow = bt * SS + mt * 128;
    int ncol0 = nt * 128;

    // A: 512 chunks of 16B (2/thread); W: 512 chunks (2/thread).
    // chunk c: line=c>>3, p=c&7, q=p^(line&7), row=2*line+(q>>2), s=q&3.
    const unsigned short* asrc[2];
    const unsigned short* wsrc[2];
    int coff[2];
#pragma unroll
    for (int i = 0; i < 2; ++i) {
        int c = t + i * 256;
        int line = c >> 3, p = c & 7, q = p ^ (line & 7);
        int row = line * 2 + (q >> 2), s = q & 3;
        asrc[i] = hidb + (size_t)(brow + row) * HH + s * 8;
        wsrc[i] = Wt + ((size_t)e << 20) + (size_t)(ncol0 + row) * HH + s * 8;
        coff[i] = c * 16;
    }

    auto stage = [&](int ks, int b) {
#pragma unroll
        for (int i = 0; i < 2; ++i)
            __builtin_amdgcn_global_load_lds(
                (const __attribute__((address_space(1))) void*)(asrc[i] + ks * 32),
                (__attribute__((address_space(3))) void*)(ldsA + b * 8192 + coff[i]),
                16, 0, 0);
#pragma unroll
        for (int i = 0; i < 2; ++i)
            __builtin_amdgcn_global_load_lds(
                (const __attribute__((address_space(1))) void*)(wsrc[i] + ks * 32),
                (__attribute__((address_space(3))) void*)(ldsW + b * 8192 + coff[i]),
                16, 0, 0);
    };

    f32x4 acc[4][4] = {};

    auto body = [&](int ks, bool do_stage) {
        const char* Af = ldsA + (ks % 3) * 8192;
        const char* Wf = ldsW + (ks % 3) * 8192;
        bhalf8 af[4], bf[4];
#pragma unroll
        for (int mf = 0; mf < 4; ++mf) {
            int r = wm * 64 + mf * 16 + l15;
            int line = r >> 1;
            int p = (g + ((r & 1) << 2)) ^ (line & 7);
            af[mf] = *reinterpret_cast<const bhalf8*>(Af + line * 128 + p * 16);
        }
#pragma unroll
        for (int nf = 0; nf < 4; ++nf) {
            int d = wn * 64 + nf * 16 + l15;
            int line = d >> 1;
            int p = (g + ((d & 1) << 2)) ^ (line & 7);
            bf[nf] = *reinterpret_cast<const bhalf8*>(Wf + line * 128 + p * 16);
        }
        if (do_stage) stage(ks + 2, (ks + 2) % 3);
        __builtin_amdgcn_s_barrier();
        __builtin_amdgcn_s_setprio(1);
#pragma unroll
        for (int mf = 0; mf < 4; ++mf)
#pragma unroll
            for (int nf = 0; nf < 4; ++nf)
                acc[mf][nf] = __builtin_amdgcn_mfma_f32_16x16x32_bf16(
                    af[mf], bf[nf], acc[mf][nf], 0, 0, 0);
        __builtin_amdgcn_s_setprio(0);
    };

    // prologue: 2 stages in flight (8 loads), wait for the first (4 remain)
    stage(0, 0); stage(1, 1);
    asm volatile("s_waitcnt vmcnt(4)" ::: "memory");
    __builtin_amdgcn_s_barrier();

    for (int ks = 0; ks < 30; ++ks) {
        body(ks, true);          // stages ks+2 (<= 31)
        asm volatile("s_waitcnt vmcnt(4)" ::: "memory");
        __builtin_amdgcn_s_barrier();
    }
    body(30, false);
    asm volatile("s_waitcnt vmcnt(0)" ::: "memory");
    __builtin_amdgcn_s_barrier();
    body(31, false);

    // ---- epilogue: bare store of y ----
#pragma unroll
    for (int nf = 0; nf < 4; ++nf) {
        int dcol = ncol0 + wn * 64 + nf * 16 + l15;
#pragma unroll
        for (int mf = 0; mf < 4; ++mf)
#pragma unroll
            for (int j = 0; j < 4; ++j) {
                int srow = brow + wm * 64 + mf * 16 + g * 4 + j;
                out[(size_t)srow * HH + dcol] = acc[mf][nf][j];
            }
    }
}

// ---------------------------------------------------------------------------
// Post: x = y + bias[e] + inp; LayerNorm(x) in place over y.
// One block per row, single pass, no atomics. XCD-matched row permutation.
// ---------------------------------------------------------------------------
__global__ __launch_bounds__(256)
void post_kernel(float* __restrict__ y, const float* __restrict__ inp,
                 const int* __restrict__ eidx, const float* __restrict__ bias,
                 const float* __restrict__ gamma, const float* __restrict__ beta)
{
    int bid = blockIdx.x;
    int row = ((bid & 7) << 10) | (bid >> 3);   // XCD-matched (8192 = 8*1024)
    int bt = row >> 9;
    int e = eidx[bt];
    int t = threadIdx.x;

    size_t base = (size_t)row * HH + t * 4;
    float4 v  = *reinterpret_cast<const float4*>(&y[base]);
    float4 iv = *reinterpret_cast<const float4*>(&inp[base]);
    float4 bv = *reinterpret_cast<const float4*>(&bias[e * HH + t * 4]);
    float4 x;
    x.x = v.x + iv.x + bv.x;
    x.y = v.y + iv.y + bv.y;
    x.z = v.z + iv.z + bv.z;
    x.w = v.w + iv.w + bv.w;

    float s1 = x.x + x.y + x.z + x.w;
    float s2 = x.x * x.x + x.y * x.y + x.z * x.z + x.w * x.w;
#pragma unroll
    for (int off = 32; off > 0; off >>= 1) {
        s1 += __shfl_xor(s1, off, 64);
        s2 += __shfl_xor(s2, off, 64);
    }
    __shared__ float red[8];
    if ((t & 63) == 0) { red[(t >> 6) * 2] = s1; red[(t >> 6) * 2 + 1] = s2; }
    __syncthreads();
    float S1 = red[0] + red[2] + red[4] + red[6];
    float S2 = red[1] + red[3] + red[5] + red[7];
    float mu  = S1 * (1.0f / HH);
    float var = S2 * (1.0f / HH) - mu * mu;
    float rs = rsqrtf(var + 1e-12f);

    float4 gv = *reinterpret_cast<const float4*>(&gamma[t * 4]);
    float4 be = *reinterpret_cast<const float4*>(&beta[t * 4]);
    float4 o;
    o.x = (x.x - mu) * rs * gv.x + be.x;
    o.y = (x.y - mu) * rs * gv.y + be.y;
    o.z = (x.z - mu) * rs * gv.z + be.z;
    o.w = (x.w - mu) * rs * gv.w + be.w;
    *reinterpret_cast<float4*>(&y[base]) = o;
}

extern "C" void kernel_launch(void* const* d_in, const int* in_sizes, int n_in,
                              void* d_out, int out_size, void* d_ws, size_t ws_size,
                              hipStream_t stream) {
    const float* hid   = (const float*)d_in[0];
    const float* inp   = (const float*)d_in[1];
    const int*   eidx  = (const int*)d_in[2];
    const float* W     = (const float*)d_in[3];
    const float* bias  = (const float*)d_in[4];
    const float* gamma = (const float*)d_in[5];
    const float* beta  = (const float*)d_in[6];
    float* out = (float*)d_out;

    unsigned short* Wt   = (unsigned short*)d_ws;                        // 16 MiB
    unsigned short* hidb = (unsigned short*)((char*)d_ws + (16u << 20)); // 16 MiB

    prep_kernel<<<6144, 256, 0, stream>>>(W, hid, eidx, Wt, hidb);
    gemm8_kernel<<<512, 256, 0, stream>>>(hidb, eidx, Wt, out);
    post_kernel<<<BB * SS, 256, 0, stream>>>(out, inp, eidx, bias, gamma, beta);
}

// Round 16
// 56.157 us; speedup vs baseline: 1.0782x; 1.0782x over previous
//
#include <hip/hip_runtime.h>
#include <hip/hip_bf16.h>

#define BB 16
#define SS 512
#define HH 1024

typedef __attribute__((ext_vector_type(4))) float f32x4;
typedef __attribute__((ext_vector_type(8))) short bhalf8;

static __device__ __forceinline__ unsigned int pack2(float a, float b) {
    __hip_bfloat162 h = __float22bfloat162_rn(make_float2(a, b));
    union { __hip_bfloat162 h; unsigned int u; } cv;
    cv.h = h;
    return cv.u;
}

static __device__ __forceinline__ unsigned short bf16u(float f) {
    union { float f; unsigned int u; } c; c.f = f;
    unsigned int r = c.u + 0x7FFFu + ((c.u >> 16) & 1u);   // RNE
    return (unsigned short)(r >> 16);
}

static __device__ __forceinline__ float ubf16(unsigned short u) {
    union { unsigned int u; float f; } c; c.u = ((unsigned int)u) << 16;
    return c.f;
}

// ---------------------------------------------------------------------------
// Prepass (all coalesced):
//   blocks [0,2048):    W[e][k][d] -> Wt[e][d][k] bf16 via LDS transpose
//   blocks [2048,6144): hid f32 -> hidb bf16
// ---------------------------------------------------------------------------
__global__ __launch_bounds__(256)
void prep_kernel(const float* __restrict__ W, const float* __restrict__ hid,
                 const int* __restrict__ eidx, unsigned short* __restrict__ Wt,
                 unsigned short* __restrict__ hidb)
{
    int bid = blockIdx.x;
    int t = threadIdx.x;
    if (bid < 2048) {
        __shared__ float lds[32 * 132];
        int e  = bid >> 8;
        bool used = false;
        for (int b = 0; b < BB; ++b) used = used || (eidx[b] == e);
        if (!used) return;
        int rem = bid & 255;
        int kt = rem >> 3, dt = rem & 7;     // 32-k x 128-d tile
#pragma unroll
        for (int i = 0; i < 4; ++i) {
            int idx = t + i * 256;
            int row = idx >> 5, col4 = idx & 31;
            float4 v = *(const float4*)(W + ((size_t)e << 20)
                        + (size_t)(kt * 32 + row) * HH + dt * 128 + col4 * 4);
            float* dst = &lds[row * 132 + col4 * 4];
            dst[0] = v.x; dst[1] = v.y; dst[2] = v.z; dst[3] = v.w;
        }
        __syncthreads();
        int d = t >> 1, kh = t & 1;
        unsigned int u[8];
#pragma unroll
        for (int p = 0; p < 8; ++p) {
            float a = lds[(kh * 16 + p * 2)     * 132 + d];
            float b = lds[(kh * 16 + p * 2 + 1) * 132 + d];
            u[p] = pack2(a, b);
        }
        unsigned short* dst = Wt + ((size_t)e << 20)
                            + (size_t)(dt * 128 + d) * HH + kt * 32 + kh * 16;
        *reinterpret_cast<uint4*>(dst)     = make_uint4(u[0], u[1], u[2], u[3]);
        *reinterpret_cast<uint4*>(dst + 8) = make_uint4(u[4], u[5], u[6], u[7]);
    } else {
        int bid2 = bid - 2048;               // 2 rows per block
        int r = bid2 * 2 + (t >> 7);
        int col = (t & 127) * 8;
        const float* src = hid + (size_t)r * HH + col;
        float4 v0 = *(const float4*)(src);
        float4 v1 = *(const float4*)(src + 4);
        uint4 o;
        o.x = pack2(v0.x, v0.y); o.y = pack2(v0.z, v0.w);
        o.z = pack2(v1.x, v1.y); o.w = pack2(v1.z, v1.w);
        *reinterpret_cast<uint4*>(hidb + (size_t)r * HH + col) = o;
    }
}

// ---------------------------------------------------------------------------
// PURE GEMM (R14 verbatim, bf16 y-store): y = hid @ W[e].
// 512 blocks x 512 thr (8 waves, 4m x 2n of 32x64), tile 128x128, BK=32,
// quad-buffered LDS (64KB -> 2 resident blocks/CU = 16 waves/CU).
// Per iter {6 ds_read; stage(ks+3) 2 loads; s_barrier; setprio+8 MFMA;
// s_waitcnt vmcnt(4); s_barrier}  (counted drain only in tail).
// pair-line XOR LDS layout (verified 0 conflicts), mfma 16x16x32 bf16.
// Epilogue stores y as bf16 (halves write traffic; ~0.004 abs error).
// ---------------------------------------------------------------------------
__global__ __launch_bounds__(512, 4)
void gemm8_kernel(const unsigned short* __restrict__ hidb,
                  const int* __restrict__ eidx,
                  const unsigned short* __restrict__ Wt,
                  unsigned short* __restrict__ ybuf)
{
    __shared__ char ldsA[4 * 8192];    // A: bf16 [128 r][32 k] per buf
    __shared__ char ldsW[4 * 8192];    // W: bf16 [128 d][32 k] per buf

    int bx  = blockIdx.x;
    int swz = (bx & 7) * 64 + (bx >> 3);      // XCD-bijective (512 % 8 == 0)
    int bt   = swz >> 5;                      // batch 0..15
    int tile = swz & 31;
    int mt = tile >> 3, nt = tile & 7;        // 4 m-tiles x 8 n-tiles
    int e = eidx[bt];

    int t = threadIdx.x, wave = t >> 6, lane = t & 63;
    int l15 = lane & 15, g = lane >> 4;
    int wm = wave >> 1, wn = wave & 1;        // 4m x 2n, wave tile 32x64

    int brow = bt * SS + mt * 128;
    int ncol0 = nt * 128;

    // A: 512 chunks of 16B (1/thread); W: 512 chunks (1/thread).
    // chunk c: line=c>>3, p=c&7, q=p^(line&7), row=2*line+(q>>2), s=q&3.
    const unsigned short* asrc;
    const unsigned short* wsrc;
    int coff;
    {
        int c = t;
        int line = c >> 3, p = c & 7, q = p ^ (line & 7);
        int row = line * 2 + (q >> 2), s = q & 3;
        asrc = hidb + (size_t)(brow + row) * HH + s * 8;
        wsrc = Wt + ((size_t)e << 20) + (size_t)(ncol0 + row) * HH + s * 8;
        coff = c * 16;
    }

    auto stage = [&](int ks, int b) {
        __builtin_amdgcn_global_load_lds(
            (const __attribute__((address_space(1))) void*)(asrc + ks * 32),
            (__attribute__((address_space(3))) void*)(ldsA + b * 8192 + coff),
            16, 0, 0);
        __builtin_amdgcn_global_load_lds(
            (const __attribute__((address_space(1))) void*)(wsrc + ks * 32),
            (__attribute__((address_space(3))) void*)(ldsW + b * 8192 + coff),
            16, 0, 0);
    };

    f32x4 acc[2][4] = {};

    auto body = [&](int ks, bool do_stage) {
        const char* Af = ldsA + (ks & 3) * 8192;
        const char* Wf = ldsW + (ks & 3) * 8192;
        bhalf8 af[2], bf[4];
#pragma unroll
        for (int mf = 0; mf < 2; ++mf) {
            int r = wm * 32 + mf * 16 + l15;
            int line = r >> 1;
            int p = (g + ((r & 1) << 2)) ^ (line & 7);
            af[mf] = *reinterpret_cast<const bhalf8*>(Af + line * 128 + p * 16);
        }
#pragma unroll
        for (int nf = 0; nf < 4; ++nf) {
            int d = wn * 64 + nf * 16 + l15;
            int line = d >> 1;
            int p = (g + ((d & 1) << 2)) ^ (line & 7);
            bf[nf] = *reinterpret_cast<const bhalf8*>(Wf + line * 128 + p * 16);
        }
        if (do_stage) stage(ks + 3, (ks + 3) & 3);
        __builtin_amdgcn_s_barrier();
        __builtin_amdgcn_s_setprio(1);
#pragma unroll
        for (int mf = 0; mf < 2; ++mf)
#pragma unroll
            for (int nf = 0; nf < 4; ++nf)
                acc[mf][nf] = __builtin_amdgcn_mfma_f32_16x16x32_bf16(
                    af[mf], bf[nf], acc[mf][nf], 0, 0, 0);
        __builtin_amdgcn_s_setprio(0);
    };

    // prologue: 3 stages in flight (6 loads), wait for the first (4 remain)
    stage(0, 0); stage(1, 1); stage(2, 2);
    asm volatile("s_waitcnt vmcnt(4)" ::: "memory");
    __builtin_amdgcn_s_barrier();

    for (int ks = 0; ks < 29; ++ks) {
        body(ks, true);
        asm volatile("s_waitcnt vmcnt(4)" ::: "memory");
        __builtin_amdgcn_s_barrier();
    }
    body(29, false);
    asm volatile("s_waitcnt vmcnt(2)" ::: "memory");
    __builtin_amdgcn_s_barrier();
    body(30, false);
    asm volatile("s_waitcnt vmcnt(0)" ::: "memory");
    __builtin_amdgcn_s_barrier();
    body(31, false);

    // ---- epilogue: store y as bf16 ----
#pragma unroll
    for (int nf = 0; nf < 4; ++nf) {
        int dcol = ncol0 + wn * 64 + nf * 16 + l15;
#pragma unroll
        for (int mf = 0; mf < 2; ++mf)
#pragma unroll
            for (int j = 0; j < 4; ++j) {
                int srow = brow + wm * 32 + mf * 16 + g * 4 + j;
                ybuf[(size_t)srow * HH + dcol] = bf16u(acc[mf][nf][j]);
            }
    }
}

// ---------------------------------------------------------------------------
// Post: x = y(bf16) + bias[e] + inp; LayerNorm(x) -> d_out (f32).
// One block per row, single pass, no atomics. XCD-matched row permutation.
// ---------------------------------------------------------------------------
__global__ __launch_bounds__(256)
void post_kernel(const unsigned short* __restrict__ ybuf,
                 const float* __restrict__ inp,
                 const int* __restrict__ eidx, const float* __restrict__ bias,
                 const float* __restrict__ gamma, const float* __restrict__ beta,
                 float* __restrict__ out)
{
    int bid = blockIdx.x;
    int row = ((bid & 7) << 10) | (bid >> 3);   // XCD-matched (8192 = 8*1024)
    int bt = row >> 9;
    int e = eidx[bt];
    int t = threadIdx.x;

    size_t base = (size_t)row * HH + t * 4;
    ushort4 yv = *reinterpret_cast<const ushort4*>(&ybuf[base]);
    float4 iv = *reinterpret_cast<const float4*>(&inp[base]);
    float4 bv = *reinterpret_cast<const float4*>(&bias[e * HH + t * 4]);
    float4 x;
    x.x = ubf16(yv.x) + iv.x + bv.x;
    x.y = ubf16(yv.y) + iv.y + bv.y;
    x.z = ubf16(yv.z) + iv.z + bv.z;
    x.w = ubf16(yv.w) + iv.w + bv.w;

    float s1 = x.x + x.y + x.z + x.w;
    float s2 = x.x * x.x + x.y * x.y + x.z * x.z + x.w * x.w;
#pragma unroll
    for (int off = 32; off > 0; off >>= 1) {
        s1 += __shfl_xor(s1, off, 64);
        s2 += __shfl_xor(s2, off, 64);
    }
    __shared__ float red[8];
    if ((t & 63) == 0) { red[(t >> 6) * 2] = s1; red[(t >> 6) * 2 + 1] = s2; }
    __syncthreads();
    float S1 = red[0] + red[2] + red[4] + red[6];
    float S2 = red[1] + red[3] + red[5] + red[7];
    float mu  = S1 * (1.0f / HH);
    float var = S2 * (1.0f / HH) - mu * mu;
    float rs = rsqrtf(var + 1e-12f);

    float4 gv = *reinterpret_cast<const float4*>(&gamma[t * 4]);
    float4 be = *reinterpret_cast<const float4*>(&beta[t * 4]);
    float4 o;
    o.x = (x.x - mu) * rs * gv.x + be.x;
    o.y = (x.y - mu) * rs * gv.y + be.y;
    o.z = (x.z - mu) * rs * gv.z + be.z;
    o.w = (x.w - mu) * rs * gv.w + be.w;
    *reinterpret_cast<float4*>(&out[base]) = o;
}

extern "C" void kernel_launch(void* const* d_in, const int* in_sizes, int n_in,
                              void* d_out, int out_size, void* d_ws, size_t ws_size,
                              hipStream_t stream) {
    const float* hid   = (const float*)d_in[0];
    const float* inp   = (const float*)d_in[1];
    const int*   eidx  = (const int*)d_in[2];
    const float* W     = (const float*)d_in[3];
    const float* bias  = (const float*)d_in[4];
    const float* gamma = (const float*)d_in[5];
    const float* beta  = (const float*)d_in[6];
    float* out = (float*)d_out;

    unsigned short* Wt   = (unsigned short*)d_ws;                        // 16 MiB
    unsigned short* hidb = (unsigned short*)((char*)d_ws + (16u << 20)); // 16 MiB
    unsigned short* ybuf = (unsigned short*)((char*)d_ws + (32u << 20)); // 16 MiB

    prep_kernel<<<6144, 256, 0, stream>>>(W, hid, eidx, Wt, hidb);
    gemm8_kernel<<<512, 512, 0, stream>>>(hidb, eidx, Wt, ybuf);
    post_kernel<<<BB * SS, 256, 0, stream>>>(ybuf, inp, eidx, bias, gamma, beta, out);
}